// Round 4
// baseline (1447.322 us; speedup 1.0000x reference)
//
#include <hip/hip_runtime.h>
#include <hip/hip_bf16.h>
#include <cstddef>

#define B_ 32
#define S_ 2048
#define H_ 1024

typedef short short8 __attribute__((ext_vector_type(8)));
typedef float floatx4 __attribute__((ext_vector_type(4)));

// packed fp32x2 -> bf16x2 (RNE), 1 VALU instr
__device__ inline unsigned int cvt_pk_bf16(float a, float b) {
    unsigned int r;
    asm("v_cvt_pk_bf16_f32 %0, %1, %2" : "=v"(r) : "v"(a), "v"(b));
    return r;
}

// async global->LDS DMA, 16B per lane; LDS dest = wave-uniform base + lane*16
__device__ inline void gload_lds16(const unsigned short* g, unsigned short* l) {
    __builtin_amdgcn_global_load_lds(
        (const __attribute__((address_space(1))) unsigned int*)g,
        (__attribute__((address_space(3))) unsigned int*)l, 16, 0, 0);
}

// ---------------- prep: enc -> tiled+swizzled bf16, W2 -> fragment-tiled bf16 ---
// encT: per (mt=m>>7, kt=k>>6) a 16KB tile: shorts[r*64 + ((j7&7)^(r&7))*8 + k&7]
// Bp:   per (nb=n>>4, kt2=k>>5) a 1KB tile, lane-linear: shorts[(lg*16+lr)*8 + k&7]
// Tail blocks zero the scores + ctx accumulators (replaces 2 hipMemsetAsync).
__global__ void prep_kernel(const float* __restrict__ enc, unsigned short* __restrict__ encT,
                            const float* __restrict__ W, unsigned short* __restrict__ Bp,
                            float* __restrict__ scores, float* __restrict__ ctx) {
    int bid = blockIdx.x, t = threadIdx.x;
    if (bid < 32768) {
        int gtid = bid * 256 + t;            // = m*128 + j7
        int m = gtid >> 7, j7 = gtid & 127;
        const float4* p = reinterpret_cast<const float4*>(enc + (size_t)m * H_ + j7 * 8);
        float4 v0 = p[0], v1 = p[1];
        union { short8 s; unsigned int u[4]; } o;
        o.u[0] = cvt_pk_bf16(v0.x, v0.y);
        o.u[1] = cvt_pk_bf16(v0.z, v0.w);
        o.u[2] = cvt_pk_bf16(v1.x, v1.y);
        o.u[3] = cvt_pk_bf16(v1.z, v1.w);
        int tile = (m >> 7) * 16 + (j7 >> 3);
        int r = m & 127;
        int j = (j7 & 7) ^ (r & 7);
        reinterpret_cast<short8*>(encT)[(size_t)tile * 1024 + r * 8 + j] = o.s;
    } else if (bid < 33280) {
        int gtid = (bid - 32768) * 256 + t;  // = n*128 + j7, n<1024
        int n = gtid >> 7, j7 = gtid & 127;
        const float4* p = reinterpret_cast<const float4*>(W + (size_t)n * 2048 + 1024 + j7 * 8);
        float4 v0 = p[0], v1 = p[1];
        union { short8 s; unsigned int u[4]; } o;
        o.u[0] = cvt_pk_bf16(v0.x, v0.y);
        o.u[1] = cvt_pk_bf16(v0.z, v0.w);
        o.u[2] = cvt_pk_bf16(v1.x, v1.y);
        o.u[3] = cvt_pk_bf16(v1.z, v1.w);
        int nb = n >> 4, lr = n & 15, kt2 = j7 >> 2, lg = j7 & 3;
        reinterpret_cast<short8*>(Bp)[(nb * 32 + kt2) * 64 + lg * 16 + lr] = o.s;
    } else {
        int z = bid - 33280;                 // 0..95
        float4 zero = {0.f, 0.f, 0.f, 0.f};
        if (z < 64) reinterpret_cast<float4*>(scores)[z * 256 + t] = zero;       // 256KB
        else        reinterpret_cast<float4*>(ctx)[(z - 64) * 256 + t] = zero;   // 128KB
    }
}

// ---------------- kernel 1: hid_proj[b][h] = hidden[b,:] . W[h, 0:1024] + bias ---
__global__ void hid_proj_kernel(const float* __restrict__ hidden,
                                const float* __restrict__ W,
                                const float* __restrict__ bias,
                                float* __restrict__ hp) {
    int h = blockIdx.x;
    int t = threadIdx.x;
    __shared__ float red[32][257];
    __shared__ float red2[32][8];
    float psum[32];
#pragma unroll
    for (int b = 0; b < 32; b++) psum[b] = 0.f;
    const float* wrow = W + (size_t)h * 2048;
    for (int c = 0; c < 4; c++) {
        int k = c * 256 + t;
        float w = wrow[k];
#pragma unroll
        for (int b = 0; b < 32; b++) psum[b] += hidden[b * 1024 + k] * w;
    }
#pragma unroll
    for (int b = 0; b < 32; b++) red[b][t] = psum[b];
    __syncthreads();
    {
        int b = t >> 3, j = t & 7;
        float s = 0.f;
#pragma unroll
        for (int q = 0; q < 32; q++) s += red[b][j * 32 + q];
        red2[b][j] = s;
    }
    __syncthreads();
    if (t < 32) {
        float tot = 0.f;
#pragma unroll
        for (int j = 0; j < 8; j++) tot += red2[t][j];
        hp[t * 1024 + h] = tot + bias[h];
    }
}

// ---------------- kernel 2: fused score GEMM (DMA A, direct-frag B) -------------
// Block 128m x 128n; grid 4096 XCD-swizzled so nt-siblings share per-XCD L2.
// A staged by global_load_lds into double-buffered LDS (pre-swizzled tiles);
// B fragments loaded straight from L2 (lane-linear packed), reg double-buffered.
// One barrier per kt.  [data path verified 238 us / MfmaUtil 24.5%]
// launch_bounds (256,5): 5 blocks/CU (LDS 5x32KB = 160KB exactly) so other
// blocks' MFMA hides each block's per-kt barrier drain (m114 TLP overlap).
__global__ __launch_bounds__(256, 5) void score_gemm_t(
    const unsigned short* __restrict__ encT,
    const unsigned short* __restrict__ Bp,
    const float* __restrict__ hp,
    const float* __restrict__ vw,
    float* __restrict__ scores)
{
    __shared__ alignas(16) unsigned short As[2][8192];

    const int tid = threadIdx.x;
    const int lane = tid & 63;
    const int w = tid >> 6, wr = w >> 1, wc = w & 1;
    const int lr = lane & 15, lg = lane >> 4;
    const int lx = lr & 7;

    const int bid = blockIdx.x;
    const int x = bid & 7, j = bid >> 3;
    const int nt = j & 7;
    const int mt = (j >> 3) * 8 + x;      // nt-siblings of mt land on XCD x

    const unsigned short* aT = encT + (size_t)mt * 16 * 8192;
    const short8* bp8 = reinterpret_cast<const short8*>(Bp);

    short8 bpf[2][8];
    // prologue: DMA A(kt=0) -> As[0]; load B(kt=0) frags
    {
        const unsigned short* src = aT + (w * 4) * 512 + lane * 8;
        unsigned short* dst = &As[0][(w * 4) * 512];
#pragma unroll
        for (int i = 0; i < 4; i++) gload_lds16(src + i * 512, dst + i * 512);
#pragma unroll
        for (int kk = 0; kk < 2; kk++)
#pragma unroll
            for (int ni = 0; ni < 4; ni++) {
                int nb = nt * 8 + wc * 4 + ni;
                bpf[0][kk * 4 + ni] = bp8[(nb * 32 + kk) * 64 + lane];
            }
    }

    floatx4 acc[4][4];
#pragma unroll
    for (int mi = 0; mi < 4; mi++)
#pragma unroll
        for (int ni = 0; ni < 4; ni++) acc[mi][ni] = (floatx4)0.f;

#pragma unroll
    for (int kt = 0; kt < 16; kt++) {
        const int cb = kt & 1;
        __syncthreads();   // DMA into As[cb] complete; prior reads of As[cb^1] done
        if (kt < 15) {
            const unsigned short* src = aT + (kt + 1) * 8192 + (w * 4) * 512 + lane * 8;
            unsigned short* dst = &As[cb ^ 1][(w * 4) * 512];
#pragma unroll
            for (int i = 0; i < 4; i++) gload_lds16(src + i * 512, dst + i * 512);
#pragma unroll
            for (int kk = 0; kk < 2; kk++)
#pragma unroll
                for (int ni = 0; ni < 4; ni++) {
                    int nb = nt * 8 + wc * 4 + ni;
                    bpf[cb ^ 1][kk * 4 + ni] = bp8[(nb * 32 + (kt + 1) * 2 + kk) * 64 + lane];
                }
        }
#pragma unroll
        for (int kk = 0; kk < 2; kk++) {
            short8 afr[4];
#pragma unroll
            for (int mi = 0; mi < 4; mi++)
                afr[mi] = *reinterpret_cast<const short8*>(
                    &As[cb][(wr * 64 + mi * 16 + lr) * 64 + ((kk * 4 + lg) ^ lx) * 8]);
#pragma unroll
            for (int mi = 0; mi < 4; mi++)
#pragma unroll
                for (int ni = 0; ni < 4; ni++)
                    acc[mi][ni] = __builtin_amdgcn_mfma_f32_16x16x32_bf16(
                        afr[mi], bpf[cb][kk * 4 + ni], acc[mi][ni], 0, 0, 0);
        }
    }

    // epilogue: tanh(e + hid_proj) * v, reduce over this block's 128 h's
    const int colBase = nt * 128 + wc * 64;
    float vv[4];
#pragma unroll
    for (int ni = 0; ni < 4; ni++) vv[ni] = vw[colBase + ni * 16 + lr];
#pragma unroll
    for (int mi = 0; mi < 4; mi++) {
        const int rowm = wr * 64 + mi * 16 + lg * 4;
#pragma unroll
        for (int i = 0; i < 4; i++) {
            const int m = mt * 128 + rowm + i;
            const int b = m & 31, sidx = m >> 5;
            const float* hprow = hp + b * H_ + colBase;
            float s = 0.f;
#pragma unroll
            for (int ni = 0; ni < 4; ni++) {
                float e = acc[mi][ni][i] + hprow[ni * 16 + lr];
                float e2 = __expf(2.0f * e);
                float th = 1.0f - 2.0f * __builtin_amdgcn_rcpf(e2 + 1.0f);
                s += th * vv[ni];
            }
            s += __shfl_xor(s, 1, 16);
            s += __shfl_xor(s, 2, 16);
            s += __shfl_xor(s, 4, 16);
            s += __shfl_xor(s, 8, 16);
            if (lr == 0) atomicAdd(&scores[b * S_ + sidx], s);
        }
    }
}

// ---------------- kernel 3: softmax over s, per b -------------------------------
__global__ void softmax_kernel(const float* __restrict__ scores, float* __restrict__ out) {
    int b = blockIdx.x, t = threadIdx.x;
    __shared__ float red[16];
    const float* row = scores + b * S_;
    float vals[8];
    float lmax = -1e30f;
#pragma unroll
    for (int i = 0; i < 8; i++) { vals[i] = row[i * 256 + t]; lmax = fmaxf(lmax, vals[i]); }
#pragma unroll
    for (int off = 32; off; off >>= 1) lmax = fmaxf(lmax, __shfl_xor(lmax, off, 64));
    if ((t & 63) == 0) red[t >> 6] = lmax;
    __syncthreads();
    float gmax = fmaxf(fmaxf(red[0], red[1]), fmaxf(red[2], red[3]));
    float lsum = 0.f;
#pragma unroll
    for (int i = 0; i < 8; i++) { vals[i] = __expf(vals[i] - gmax); lsum += vals[i]; }
#pragma unroll
    for (int off = 32; off; off >>= 1) lsum += __shfl_xor(lsum, off, 64);
    if ((t & 63) == 0) red[8 + (t >> 6)] = lsum;
    __syncthreads();
    float inv = 1.0f / (red[8] + red[9] + red[10] + red[11]);
#pragma unroll
    for (int i = 0; i < 8; i++) out[b * S_ + i * 256 + t] = vals[i] * inv;
}

// ---------------- kernel 4: context from tiled bf16 encT (known-good) -----------
__global__ void context_tiled(const unsigned short* __restrict__ encT,
                              const float* __restrict__ wts,
                              float* __restrict__ ctx) {
    int t = threadIdx.x;
    int hc = blockIdx.x & 1;
    int b = (blockIdx.x >> 1) & 31;
    int sc = blockIdx.x >> 6;            // 0..15
    int h = hc * 512 + t * 2;
    const float* w = wts + b * S_ + sc * 128;
    const int jconst = ((h >> 3) & 7) ^ (b & 7);
    const int inrow = jconst * 8 + (h & 7);
    const int ktile = h >> 6;
    float acc0 = 0.f, acc1 = 0.f;
#pragma unroll 4
    for (int s = 0; s < 128; s++) {
        int m = (sc * 128 + s) * 32 + b;
        size_t off = ((size_t)(m >> 7) * 16 + ktile) * 8192 + (m & 127) * 64 + inrow;
        unsigned int u = *reinterpret_cast<const unsigned int*>(encT + off);
        float ws_ = w[s];
        acc0 += ws_ * __uint_as_float(u << 16);
        acc1 += ws_ * __uint_as_float(u & 0xffff0000u);
    }
    atomicAdd(&ctx[b * H_ + h], acc0);
    atomicAdd(&ctx[b * H_ + h + 1], acc1);
}

// ================= fallback path (small workspace): round-3 kernels =============
__global__ void pack_w2_rm(const float* __restrict__ W, unsigned short* __restrict__ W2) {
    int i = blockIdx.x * 256 + threadIdx.x;
    int n = i >> 8;
    int k4 = (i & 255) * 4;
    float4 v = *reinterpret_cast<const float4*>(W + (size_t)n * 2048 + 1024 + k4);
    uint2 o;
    o.x = cvt_pk_bf16(v.x, v.y);
    o.y = cvt_pk_bf16(v.z, v.w);
    *reinterpret_cast<uint2*>(W2 + (size_t)n * 1024 + k4) = o;
}

__global__ __launch_bounds__(256, 3) void score_gemm_f32(
    const float* __restrict__ Ap, const unsigned short* __restrict__ W2,
    const float* __restrict__ hp, const float* __restrict__ vw,
    float* __restrict__ scores)
{
    __shared__ alignas(16) unsigned short As[128 * 64];
    __shared__ alignas(16) unsigned short Bs[128 * 64];
    const int tid = threadIdx.x;
    const int lane = tid & 63;
    const int w = tid >> 6, wr = w >> 1, wc = w & 1;
    const int lr = lane & 15, lg = lane >> 4;
    const int bid = blockIdx.x;
    const int nt = bid & 7, mt = bid >> 3;
    const int row = tid >> 1, half = tid & 1;
    const int xk = row & 7;
    const int lx = lr & 7;
    const float* aF = Ap + (size_t)(mt * 128 + row) * H_ + half * 32;
    const unsigned short* bP = W2 + (size_t)(nt * 128 + row) * H_ + half * 32;
    short8 b8[4]; float4 af[8];
    {
        const float4* p = reinterpret_cast<const float4*>(aF);
#pragma unroll
        for (int i = 0; i < 8; i++) af[i] = p[i];
        const short8* q = reinterpret_cast<const short8*>(bP);
#pragma unroll
        for (int i = 0; i < 4; i++) b8[i] = q[i];
    }
    floatx4 acc[4][4];
#pragma unroll
    for (int mi = 0; mi < 4; mi++)
#pragma unroll
        for (int ni = 0; ni < 4; ni++) acc[mi][ni] = (floatx4)0.f;
    for (int kt = 0; kt < 16; kt++) {
        __syncthreads();
#pragma unroll
        for (int i = 0; i < 4; i++) {
            union { short8 s; unsigned int u[4]; } o;
            o.u[0] = cvt_pk_bf16(af[2 * i].x, af[2 * i].y);
            o.u[1] = cvt_pk_bf16(af[2 * i].z, af[2 * i].w);
            o.u[2] = cvt_pk_bf16(af[2 * i + 1].x, af[2 * i + 1].y);
            o.u[3] = cvt_pk_bf16(af[2 * i + 1].z, af[2 * i + 1].w);
            *reinterpret_cast<short8*>(&As[row * 64 + ((half * 4 + i) ^ xk) * 8]) = o.s;
        }
#pragma unroll
        for (int i = 0; i < 4; i++)
            *reinterpret_cast<short8*>(&Bs[row * 64 + ((half * 4 + i) ^ xk) * 8]) = b8[i];
        __syncthreads();
        if (kt < 15) {
            const float4* p = reinterpret_cast<const float4*>(aF + (kt + 1) * 64);
#pragma unroll
            for (int i = 0; i < 8; i++) af[i] = p[i];
            const short8* q = reinterpret_cast<const short8*>(bP + (kt + 1) * 64);
#pragma unroll
            for (int i = 0; i < 4; i++) b8[i] = q[i];
        }
#pragma unroll
        for (int kk = 0; kk < 2; kk++) {
            const int g = (kk * 4 + lg) ^ lx;
            short8 afr[4], bfr[4];
#pragma unroll
            for (int mi = 0; mi < 4; mi++)
                afr[mi] = *reinterpret_cast<const short8*>(&As[(wr * 64 + mi * 16 + lr) * 64 + g * 8]);
#pragma unroll
            for (int ni = 0; ni < 4; ni++)
                bfr[ni] = *reinterpret_cast<const short8*>(&Bs[(wc * 64 + ni * 16 + lr) * 64 + g * 8]);
#pragma unroll
            for (int mi = 0; mi < 4; mi++)
#pragma unroll
                for (int ni = 0; ni < 4; ni++)
                    acc[mi][ni] = __builtin_amdgcn_mfma_f32_16x16x32_bf16(
                        afr[mi], bfr[ni], acc[mi][ni], 0, 0, 0);
        }
    }
    const int colBase = nt * 128 + wc * 64;
    float vv[4];
#pragma unroll
    for (int ni = 0; ni < 4; ni++) vv[ni] = vw[colBase + ni * 16 + lr];
#pragma unroll
    for (int mi = 0; mi < 4; mi++) {
        const int rowm = wr * 64 + mi * 16 + lg * 4;
#pragma unroll
        for (int i = 0; i < 4; i++) {
            const int m = mt * 128 + rowm + i;
            const int b = m & 31, sidx = m >> 5;
            const float* hprow = hp + b * H_ + colBase;
            float s = 0.f;
#pragma unroll
            for (int ni = 0; ni < 4; ni++) {
                float e = acc[mi][ni][i] + hprow[ni * 16 + lr];
                float e2 = __expf(2.0f * e);
                float th = 1.0f - 2.0f * __builtin_amdgcn_rcpf(e2 + 1.0f);
                s += th * vv[ni];
            }
            s += __shfl_xor(s, 1, 16);
            s += __shfl_xor(s, 2, 16);
            s += __shfl_xor(s, 4, 16);
            s += __shfl_xor(s, 8, 16);
            if (lr == 0) atomicAdd(&scores[b * S_ + sidx], s);
        }
    }
}

__global__ void context_f32(const float* __restrict__ enc,
                            const float* __restrict__ wts,
                            float* __restrict__ ctx) {
    int t = threadIdx.x;
    int hc = blockIdx.x & 1;
    int b = (blockIdx.x >> 1) & 31;
    int sc = blockIdx.x >> 6;
    int h = hc * 512 + t * 2;
    const float* w = wts + b * S_ + sc * 128;
    const float* e = enc + (size_t)(sc * 128) * (B_ * H_) + b * H_ + h;
    float acc0 = 0.f, acc1 = 0.f;
#pragma unroll 8
    for (int s = 0; s < 128; s++) {
        float ws_ = w[s];
        acc0 += ws_ * e[(size_t)s * (B_ * H_)];
        acc1 += ws_ * e[(size_t)s * (B_ * H_) + 1];
    }
    atomicAdd(&ctx[b * H_ + h], acc0);
    atomicAdd(&ctx[b * H_ + h + 1], acc1);
}

extern "C" void kernel_launch(void* const* d_in, const int* in_sizes, int n_in,
                              void* d_out, int out_size, void* d_ws, size_t ws_size,
                              hipStream_t stream) {
    const float* hidden = (const float*)d_in[0];
    const float* enc    = (const float*)d_in[1];
    const float* attn_W = (const float*)d_in[2];
    const float* attn_b = (const float*)d_in[3];
    const float* v_W    = (const float*)d_in[4];
    float* out = (float*)d_out;

    char* ws = (char*)d_ws;
    const size_t ENCT_BYTES = (size_t)S_ * B_ * H_ * 2;   // 128 MiB
    const size_t BP_BYTES   = (size_t)H_ * H_ * 2;        // 2 MiB
    const bool big = ws_size >= ENCT_BYTES + BP_BYTES + (1u << 20);

    if (big) {
        unsigned short* encT = (unsigned short*)ws;
        unsigned short* Bp   = (unsigned short*)(ws + ENCT_BYTES);
        float* hp     = (float*)(ws + ENCT_BYTES + BP_BYTES);
        float* scores = (float*)(ws + ENCT_BYTES + BP_BYTES + (256u << 10));

        prep_kernel<<<33376, 256, 0, stream>>>(enc, encT, attn_W, Bp, scores, out);
        hid_proj_kernel<<<1024, 256, 0, stream>>>(hidden, attn_W, attn_b, hp);
        score_gemm_t<<<4096, 256, 0, stream>>>(encT, Bp, hp, v_W, scores);
        softmax_kernel<<<32, 256, 0, stream>>>(scores, out + B_ * H_);
        context_tiled<<<1024, 256, 0, stream>>>(encT, out + B_ * H_, out);
    } else {
        unsigned short* W2bf = (unsigned short*)ws;
        float* hp     = (float*)(ws + BP_BYTES);
        float* scores = (float*)(ws + BP_BYTES + (256u << 10));

        pack_w2_rm<<<1024, 256, 0, stream>>>(attn_W, W2bf);
        hid_proj_kernel<<<1024, 256, 0, stream>>>(hidden, attn_W, attn_b, hp);
        hipMemsetAsync(scores, 0, B_ * S_ * sizeof(float), stream);
        score_gemm_f32<<<4096, 256, 0, stream>>>(enc, W2bf, hp, v_W, scores);
        softmax_kernel<<<32, 256, 0, stream>>>(scores, out + B_ * H_);
        hipMemsetAsync(out, 0, B_ * H_ * sizeof(float), stream);
        context_f32<<<1024, 256, 0, stream>>>(enc, out + B_ * H_, out);
    }
}

// Round 5
// 638.609 us; speedup vs baseline: 2.2664x; 2.2664x over previous
//
#include <hip/hip_runtime.h>
#include <hip/hip_bf16.h>
#include <cstddef>

#define B_ 32
#define S_ 2048
#define H_ 1024

typedef short short8 __attribute__((ext_vector_type(8)));
typedef float floatx4 __attribute__((ext_vector_type(4)));

// packed fp32x2 -> bf16x2 (RNE), 1 VALU instr
__device__ inline unsigned int cvt_pk_bf16(float a, float b) {
    unsigned int r;
    asm("v_cvt_pk_bf16_f32 %0, %1, %2" : "=v"(r) : "v"(a), "v"(b));
    return r;
}

// async global->LDS DMA, 16B per lane; LDS dest = wave-uniform base + lane*16
__device__ inline void gload_lds16(const unsigned short* g, unsigned short* l) {
    __builtin_amdgcn_global_load_lds(
        (const __attribute__((address_space(1))) unsigned int*)g,
        (__attribute__((address_space(3))) unsigned int*)l, 16, 0, 0);
}

// ---------------- prep: enc -> tiled+swizzled bf16, W2 -> fragment-tiled bf16 ---
// encT: per (mt=m>>7, kt=k>>6) a 16KB tile: shorts[r*64 + ((j7&7)^(r&7))*8 + k&7]
// NEW layout of work: one block per (mt,kt) tile -> dest writes are LINEAR
// (thread t writes chunk i*256+t of its tile); source reads are an XOR permute
// within a 256B window (same cache lines, still coalesced).
// Bp:   per (nb=n>>4, kt2=k>>5) a 1KB tile, lane-linear: shorts[(lg*16+lr)*8 + k&7]
// Tail blocks zero the scores + ctx accumulators (replaces 2 hipMemsetAsync;
// measured neutral vs separate memsets, saves 2 dispatch gaps).
__global__ void prep_kernel(const float* __restrict__ enc, unsigned short* __restrict__ encT,
                            const float* __restrict__ W, unsigned short* __restrict__ Bp,
                            float* __restrict__ scores, float* __restrict__ ctx) {
    int bid = blockIdx.x, t = threadIdx.x;
    if (bid < 8192) {                        // tile = bid = mt*16 + kt
        const float* src = enc + (size_t)(bid >> 4) * (128 * 1024) + (bid & 15) * 64;
        short8* dst = reinterpret_cast<short8*>(encT) + (size_t)bid * 1024;
#pragma unroll
        for (int i = 0; i < 4; i++) {
            int r = i * 32 + (t >> 3);
            int jsrc = (t & 7) ^ (r & 7);
            const float4* p = reinterpret_cast<const float4*>(src + (size_t)r * 1024 + jsrc * 8);
            float4 v0 = p[0], v1 = p[1];
            union { short8 s; unsigned int u[4]; } o;
            o.u[0] = cvt_pk_bf16(v0.x, v0.y);
            o.u[1] = cvt_pk_bf16(v0.z, v0.w);
            o.u[2] = cvt_pk_bf16(v1.x, v1.y);
            o.u[3] = cvt_pk_bf16(v1.z, v1.w);
            dst[i * 256 + t] = o.s;          // linear: i*256+t == r*8 + jdst
        }
    } else if (bid < 8704) {
        int gtid = (bid - 8192) * 256 + t;   // = n*128 + j7, n<1024
        int n = gtid >> 7, j7 = gtid & 127;
        const float4* p = reinterpret_cast<const float4*>(W + (size_t)n * 2048 + 1024 + j7 * 8);
        float4 v0 = p[0], v1 = p[1];
        union { short8 s; unsigned int u[4]; } o;
        o.u[0] = cvt_pk_bf16(v0.x, v0.y);
        o.u[1] = cvt_pk_bf16(v0.z, v0.w);
        o.u[2] = cvt_pk_bf16(v1.x, v1.y);
        o.u[3] = cvt_pk_bf16(v1.z, v1.w);
        int nb = n >> 4, lr = n & 15, kt2 = j7 >> 2, lg = j7 & 3;
        reinterpret_cast<short8*>(Bp)[(nb * 32 + kt2) * 64 + lg * 16 + lr] = o.s;
    } else {
        int z = bid - 8704;                  // 0..95
        float4 zero = {0.f, 0.f, 0.f, 0.f};
        if (z < 64) reinterpret_cast<float4*>(scores)[z * 256 + t] = zero;       // 256KB
        else        reinterpret_cast<float4*>(ctx)[(z - 64) * 256 + t] = zero;   // 128KB
    }
}

// ---------------- kernel 1: hid_proj[b][h] = hidden[b,:] . W[h, 0:1024] + bias ---
__global__ void hid_proj_kernel(const float* __restrict__ hidden,
                                const float* __restrict__ W,
                                const float* __restrict__ bias,
                                float* __restrict__ hp) {
    int h = blockIdx.x;
    int t = threadIdx.x;
    __shared__ float red[32][257];
    __shared__ float red2[32][8];
    float psum[32];
#pragma unroll
    for (int b = 0; b < 32; b++) psum[b] = 0.f;
    const float* wrow = W + (size_t)h * 2048;
    for (int c = 0; c < 4; c++) {
        int k = c * 256 + t;
        float w = wrow[k];
#pragma unroll
        for (int b = 0; b < 32; b++) psum[b] += hidden[b * 1024 + k] * w;
    }
#pragma unroll
    for (int b = 0; b < 32; b++) red[b][t] = psum[b];
    __syncthreads();
    {
        int b = t >> 3, j = t & 7;
        float s = 0.f;
#pragma unroll
        for (int q = 0; q < 32; q++) s += red[b][j * 32 + q];
        red2[b][j] = s;
    }
    __syncthreads();
    if (t < 32) {
        float tot = 0.f;
#pragma unroll
        for (int j = 0; j < 8; j++) tot += red2[t][j];
        hp[t * 1024 + h] = tot + bias[h];
    }
}

// ---------------- kernel 2: fused score GEMM (DMA A, direct-frag B) -------------
// Block 128m x 128n; grid 4096 XCD-swizzled so nt-siblings share per-XCD L2.
// A staged by global_load_lds into double-buffered LDS (pre-swizzled tiles);
// B fragments loaded straight from L2 (lane-linear packed), reg double-buffered.
// One barrier per kt.  [verified 238 us / MfmaUtil 24.5% / VGPR 80]
// NOTE: bound must stay 3 (<=4). (256,5) forces VGPR<=64 -> accumulator spills
// to scratch (R4: 2.7GB scratch writes, 4.5x slowdown). VGPR=80 already permits
// 4 blocks/CU in HW; launch_bounds cannot raise real occupancy.
__global__ __launch_bounds__(256, 3) void score_gemm_t(
    const unsigned short* __restrict__ encT,
    const unsigned short* __restrict__ Bp,
    const float* __restrict__ hp,
    const float* __restrict__ vw,
    float* __restrict__ scores)
{
    __shared__ alignas(16) unsigned short As[2][8192];

    const int tid = threadIdx.x;
    const int lane = tid & 63;
    const int w = tid >> 6, wr = w >> 1, wc = w & 1;
    const int lr = lane & 15, lg = lane >> 4;
    const int lx = lr & 7;

    const int bid = blockIdx.x;
    const int x = bid & 7, j = bid >> 3;
    const int nt = j & 7;
    const int mt = (j >> 3) * 8 + x;      // nt-siblings of mt land on XCD x

    const unsigned short* aT = encT + (size_t)mt * 16 * 8192;
    const short8* bp8 = reinterpret_cast<const short8*>(Bp);

    short8 bpf[2][8];
    // prologue: DMA A(kt=0) -> As[0]; load B(kt=0) frags
    {
        const unsigned short* src = aT + (w * 4) * 512 + lane * 8;
        unsigned short* dst = &As[0][(w * 4) * 512];
#pragma unroll
        for (int i = 0; i < 4; i++) gload_lds16(src + i * 512, dst + i * 512);
#pragma unroll
        for (int kk = 0; kk < 2; kk++)
#pragma unroll
            for (int ni = 0; ni < 4; ni++) {
                int nb = nt * 8 + wc * 4 + ni;
                bpf[0][kk * 4 + ni] = bp8[(nb * 32 + kk) * 64 + lane];
            }
    }

    floatx4 acc[4][4];
#pragma unroll
    for (int mi = 0; mi < 4; mi++)
#pragma unroll
        for (int ni = 0; ni < 4; ni++) acc[mi][ni] = (floatx4)0.f;

#pragma unroll
    for (int kt = 0; kt < 16; kt++) {
        const int cb = kt & 1;
        __syncthreads();   // DMA into As[cb] complete; prior reads of As[cb^1] done
        if (kt < 15) {
            const unsigned short* src = aT + (kt + 1) * 8192 + (w * 4) * 512 + lane * 8;
            unsigned short* dst = &As[cb ^ 1][(w * 4) * 512];
#pragma unroll
            for (int i = 0; i < 4; i++) gload_lds16(src + i * 512, dst + i * 512);
#pragma unroll
            for (int kk = 0; kk < 2; kk++)
#pragma unroll
                for (int ni = 0; ni < 4; ni++) {
                    int nb = nt * 8 + wc * 4 + ni;
                    bpf[cb ^ 1][kk * 4 + ni] = bp8[(nb * 32 + (kt + 1) * 2 + kk) * 64 + lane];
                }
        }
#pragma unroll
        for (int kk = 0; kk < 2; kk++) {
            short8 afr[4];
#pragma unroll
            for (int mi = 0; mi < 4; mi++)
                afr[mi] = *reinterpret_cast<const short8*>(
                    &As[cb][(wr * 64 + mi * 16 + lr) * 64 + ((kk * 4 + lg) ^ lx) * 8]);
#pragma unroll
            for (int mi = 0; mi < 4; mi++)
#pragma unroll
                for (int ni = 0; ni < 4; ni++)
                    acc[mi][ni] = __builtin_amdgcn_mfma_f32_16x16x32_bf16(
                        afr[mi], bpf[cb][kk * 4 + ni], acc[mi][ni], 0, 0, 0);
        }
    }

    // epilogue: tanh(e + hid_proj) * v, reduce over this block's 128 h's
    const int colBase = nt * 128 + wc * 64;
    float vv[4];
#pragma unroll
    for (int ni = 0; ni < 4; ni++) vv[ni] = vw[colBase + ni * 16 + lr];
#pragma unroll
    for (int mi = 0; mi < 4; mi++) {
        const int rowm = wr * 64 + mi * 16 + lg * 4;
#pragma unroll
        for (int i = 0; i < 4; i++) {
            const int m = mt * 128 + rowm + i;
            const int b = m & 31, sidx = m >> 5;
            const float* hprow = hp + b * H_ + colBase;
            float s = 0.f;
#pragma unroll
            for (int ni = 0; ni < 4; ni++) {
                float e = acc[mi][ni][i] + hprow[ni * 16 + lr];
                float e2 = __expf(2.0f * e);
                float th = 1.0f - 2.0f * __builtin_amdgcn_rcpf(e2 + 1.0f);
                s += th * vv[ni];
            }
            s += __shfl_xor(s, 1, 16);
            s += __shfl_xor(s, 2, 16);
            s += __shfl_xor(s, 4, 16);
            s += __shfl_xor(s, 8, 16);
            if (lr == 0) atomicAdd(&scores[b * S_ + sidx], s);
        }
    }
}

// ---------------- kernel 3: softmax over s, per b -------------------------------
__global__ void softmax_kernel(const float* __restrict__ scores, float* __restrict__ out) {
    int b = blockIdx.x, t = threadIdx.x;
    __shared__ float red[16];
    const float* row = scores + b * S_;
    float vals[8];
    float lmax = -1e30f;
#pragma unroll
    for (int i = 0; i < 8; i++) { vals[i] = row[i * 256 + t]; lmax = fmaxf(lmax, vals[i]); }
#pragma unroll
    for (int off = 32; off; off >>= 1) lmax = fmaxf(lmax, __shfl_xor(lmax, off, 64));
    if ((t & 63) == 0) red[t >> 6] = lmax;
    __syncthreads();
    float gmax = fmaxf(fmaxf(red[0], red[1]), fmaxf(red[2], red[3]));
    float lsum = 0.f;
#pragma unroll
    for (int i = 0; i < 8; i++) { vals[i] = __expf(vals[i] - gmax); lsum += vals[i]; }
#pragma unroll
    for (int off = 32; off; off >>= 1) lsum += __shfl_xor(lsum, off, 64);
    if ((t & 63) == 0) red[8 + (t >> 6)] = lsum;
    __syncthreads();
    float inv = 1.0f / (red[8] + red[9] + red[10] + red[11]);
#pragma unroll
    for (int i = 0; i < 8; i++) out[b * S_ + i * 256 + t] = vals[i] * inv;
}

// ---------------- kernel 4: context from tiled bf16 encT (known-good) -----------
__global__ void context_tiled(const unsigned short* __restrict__ encT,
                              const float* __restrict__ wts,
                              float* __restrict__ ctx) {
    int t = threadIdx.x;
    int hc = blockIdx.x & 1;
    int b = (blockIdx.x >> 1) & 31;
    int sc = blockIdx.x >> 6;            // 0..15
    int h = hc * 512 + t * 2;
    const float* w = wts + b * S_ + sc * 128;
    const int jconst = ((h >> 3) & 7) ^ (b & 7);
    const int inrow = jconst * 8 + (h & 7);
    const int ktile = h >> 6;
    float acc0 = 0.f, acc1 = 0.f;
#pragma unroll 4
    for (int s = 0; s < 128; s++) {
        int m = (sc * 128 + s) * 32 + b;
        size_t off = ((size_t)(m >> 7) * 16 + ktile) * 8192 + (m & 127) * 64 + inrow;
        unsigned int u = *reinterpret_cast<const unsigned int*>(encT + off);
        float ws_ = w[s];
        acc0 += ws_ * __uint_as_float(u << 16);
        acc1 += ws_ * __uint_as_float(u & 0xffff0000u);
    }
    atomicAdd(&ctx[b * H_ + h], acc0);
    atomicAdd(&ctx[b * H_ + h + 1], acc1);
}

// ================= fallback path (small workspace): round-3 kernels =============
__global__ void pack_w2_rm(const float* __restrict__ W, unsigned short* __restrict__ W2) {
    int i = blockIdx.x * 256 + threadIdx.x;
    int n = i >> 8;
    int k4 = (i & 255) * 4;
    float4 v = *reinterpret_cast<const float4*>(W + (size_t)n * 2048 + 1024 + k4);
    uint2 o;
    o.x = cvt_pk_bf16(v.x, v.y);
    o.y = cvt_pk_bf16(v.z, v.w);
    *reinterpret_cast<uint2*>(W2 + (size_t)n * 1024 + k4) = o;
}

__global__ __launch_bounds__(256, 3) void score_gemm_f32(
    const float* __restrict__ Ap, const unsigned short* __restrict__ W2,
    const float* __restrict__ hp, const float* __restrict__ vw,
    float* __restrict__ scores)
{
    __shared__ alignas(16) unsigned short As[128 * 64];
    __shared__ alignas(16) unsigned short Bs[128 * 64];
    const int tid = threadIdx.x;
    const int lane = tid & 63;
    const int w = tid >> 6, wr = w >> 1, wc = w & 1;
    const int lr = lane & 15, lg = lane >> 4;
    const int bid = blockIdx.x;
    const int nt = bid & 7, mt = bid >> 3;
    const int row = tid >> 1, half = tid & 1;
    const int xk = row & 7;
    const int lx = lr & 7;
    const float* aF = Ap + (size_t)(mt * 128 + row) * H_ + half * 32;
    const unsigned short* bP = W2 + (size_t)(nt * 128 + row) * H_ + half * 32;
    short8 b8[4]; float4 af[8];
    {
        const float4* p = reinterpret_cast<const float4*>(aF);
#pragma unroll
        for (int i = 0; i < 8; i++) af[i] = p[i];
        const short8* q = reinterpret_cast<const short8*>(bP);
#pragma unroll
        for (int i = 0; i < 4; i++) b8[i] = q[i];
    }
    floatx4 acc[4][4];
#pragma unroll
    for (int mi = 0; mi < 4; mi++)
#pragma unroll
        for (int ni = 0; ni < 4; ni++) acc[mi][ni] = (floatx4)0.f;
    for (int kt = 0; kt < 16; kt++) {
        __syncthreads();
#pragma unroll
        for (int i = 0; i < 4; i++) {
            union { short8 s; unsigned int u[4]; } o;
            o.u[0] = cvt_pk_bf16(af[2 * i].x, af[2 * i].y);
            o.u[1] = cvt_pk_bf16(af[2 * i].z, af[2 * i].w);
            o.u[2] = cvt_pk_bf16(af[2 * i + 1].x, af[2 * i + 1].y);
            o.u[3] = cvt_pk_bf16(af[2 * i + 1].z, af[2 * i + 1].w);
            *reinterpret_cast<short8*>(&As[row * 64 + ((half * 4 + i) ^ xk) * 8]) = o.s;
        }
#pragma unroll
        for (int i = 0; i < 4; i++)
            *reinterpret_cast<short8*>(&Bs[row * 64 + ((half * 4 + i) ^ xk) * 8]) = b8[i];
        __syncthreads();
        if (kt < 15) {
            const float4* p = reinterpret_cast<const float4*>(aF + (kt + 1) * 64);
#pragma unroll
            for (int i = 0; i < 8; i++) af[i] = p[i];
            const short8* q = reinterpret_cast<const short8*>(bP + (kt + 1) * 64);
#pragma unroll
            for (int i = 0; i < 4; i++) b8[i] = q[i];
        }
#pragma unroll
        for (int kk = 0; kk < 2; kk++) {
            const int g = (kk * 4 + lg) ^ lx;
            short8 afr[4], bfr[4];
#pragma unroll
            for (int mi = 0; mi < 4; mi++)
                afr[mi] = *reinterpret_cast<const short8*>(&As[(wr * 64 + mi * 16 + lr) * 64 + g * 8]);
#pragma unroll
            for (int ni = 0; ni < 4; ni++)
                bfr[ni] = *reinterpret_cast<const short8*>(&Bs[(wc * 64 + ni * 16 + lr) * 64 + g * 8]);
#pragma unroll
            for (int mi = 0; mi < 4; mi++)
#pragma unroll
                for (int ni = 0; ni < 4; ni++)
                    acc[mi][ni] = __builtin_amdgcn_mfma_f32_16x16x32_bf16(
                        afr[mi], bfr[ni], acc[mi][ni], 0, 0, 0);
        }
    }
    const int colBase = nt * 128 + wc * 64;
    float vv[4];
#pragma unroll
    for (int ni = 0; ni < 4; ni++) vv[ni] = vw[colBase + ni * 16 + lr];
#pragma unroll
    for (int mi = 0; mi < 4; mi++) {
        const int rowm = wr * 64 + mi * 16 + lg * 4;
#pragma unroll
        for (int i = 0; i < 4; i++) {
            const int m = mt * 128 + rowm + i;
            const int b = m & 31, sidx = m >> 5;
            const float* hprow = hp + b * H_ + colBase;
            float s = 0.f;
#pragma unroll
            for (int ni = 0; ni < 4; ni++) {
                float e = acc[mi][ni][i] + hprow[ni * 16 + lr];
                float e2 = __expf(2.0f * e);
                float th = 1.0f - 2.0f * __builtin_amdgcn_rcpf(e2 + 1.0f);
                s += th * vv[ni];
            }
            s += __shfl_xor(s, 1, 16);
            s += __shfl_xor(s, 2, 16);
            s += __shfl_xor(s, 4, 16);
            s += __shfl_xor(s, 8, 16);
            if (lr == 0) atomicAdd(&scores[b * S_ + sidx], s);
        }
    }
}

__global__ void context_f32(const float* __restrict__ enc,
                            const float* __restrict__ wts,
                            float* __restrict__ ctx) {
    int t = threadIdx.x;
    int hc = blockIdx.x & 1;
    int b = (blockIdx.x >> 1) & 31;
    int sc = blockIdx.x >> 6;
    int h = hc * 512 + t * 2;
    const float* w = wts + b * S_ + sc * 128;
    const float* e = enc + (size_t)(sc * 128) * (B_ * H_) + b * H_ + h;
    float acc0 = 0.f, acc1 = 0.f;
#pragma unroll 8
    for (int s = 0; s < 128; s++) {
        float ws_ = w[s];
        acc0 += ws_ * e[(size_t)s * (B_ * H_)];
        acc1 += ws_ * e[(size_t)s * (B_ * H_) + 1];
    }
    atomicAdd(&ctx[b * H_ + h], acc0);
    atomicAdd(&ctx[b * H_ + h + 1], acc1);
}

extern "C" void kernel_launch(void* const* d_in, const int* in_sizes, int n_in,
                              void* d_out, int out_size, void* d_ws, size_t ws_size,
                              hipStream_t stream) {
    const float* hidden = (const float*)d_in[0];
    const float* enc    = (const float*)d_in[1];
    const float* attn_W = (const float*)d_in[2];
    const float* attn_b = (const float*)d_in[3];
    const float* v_W    = (const float*)d_in[4];
    float* out = (float*)d_out;

    char* ws = (char*)d_ws;
    const size_t ENCT_BYTES = (size_t)S_ * B_ * H_ * 2;   // 128 MiB
    const size_t BP_BYTES   = (size_t)H_ * H_ * 2;        // 2 MiB
    const bool big = ws_size >= ENCT_BYTES + BP_BYTES + (1u << 20);

    if (big) {
        unsigned short* encT = (unsigned short*)ws;
        unsigned short* Bp   = (unsigned short*)(ws + ENCT_BYTES);
        float* hp     = (float*)(ws + ENCT_BYTES + BP_BYTES);
        float* scores = (float*)(ws + ENCT_BYTES + BP_BYTES + (256u << 10));

        prep_kernel<<<8800, 256, 0, stream>>>(enc, encT, attn_W, Bp, scores, out);
        hid_proj_kernel<<<1024, 256, 0, stream>>>(hidden, attn_W, attn_b, hp);
        score_gemm_t<<<4096, 256, 0, stream>>>(encT, Bp, hp, v_W, scores);
        softmax_kernel<<<32, 256, 0, stream>>>(scores, out + B_ * H_);
        context_tiled<<<1024, 256, 0, stream>>>(encT, out + B_ * H_, out);
    } else {
        unsigned short* W2bf = (unsigned short*)ws;
        float* hp     = (float*)(ws + BP_BYTES);
        float* scores = (float*)(ws + BP_BYTES + (256u << 10));

        pack_w2_rm<<<1024, 256, 0, stream>>>(attn_W, W2bf);
        hid_proj_kernel<<<1024, 256, 0, stream>>>(hidden, attn_W, attn_b, hp);
        hipMemsetAsync(scores, 0, B_ * S_ * sizeof(float), stream);
        score_gemm_f32<<<4096, 256, 0, stream>>>(enc, W2bf, hp, v_W, scores);
        softmax_kernel<<<32, 256, 0, stream>>>(scores, out + B_ * H_);
        hipMemsetAsync(out, 0, B_ * H_ * sizeof(float), stream);
        context_f32<<<1024, 256, 0, stream>>>(enc, out + B_ * H_, out);
    }
}